// Round 20
// baseline (302.198 us; speedup 1.0000x reference)
//
#include <hip/hip_runtime.h>
#include <hip/hip_fp16.h>

#define MAXD 10
#define TSTEPS 4
#define KD 80      // IN + EC
#define IN 64
#define ECH 16
#define TILE_N 64   // nodes per block in y_kernel
#define TILE_Z 128  // edges per block in zgemm (512 thr: 32 groups x 4 edges)
#define SCAN_CHUNK 1024

#define AGG_BLOCK 256
#define AGG_DPB (AGG_BLOCK / 16)   // 16 dsts per block (one per 16-lane group)

__device__ __forceinline__ float sigmoidf(float v) {
    return 1.0f / (1.0f + __expf(-v));
}

// ---------------- preprocessing ----------------
// deg[] counts out-edges EXCLUDING self loop; bucket = min(deg, MAXD-1).

__global__ __launch_bounds__(256) void hist_kernel(const int* __restrict__ ei,
                                                   int* deg, int* in_cnt, int E) {
    int e = blockIdx.x * 256 + threadIdx.x;
    if (e < E) {
        atomicAdd(&deg[ei[e]], 1);
        atomicAdd(&in_cnt[ei[E + e]], 1);
    }
}

// scanA: block partial sums of in_cnt; fused node-bucket AND edge-bucket
// histograms (edge count per bucket = sum of deg over nodes in that bucket).
__global__ __launch_bounds__(256) void scanA_kernel(const int* __restrict__ in_cnt,
                                                    const int* __restrict__ deg,
                                                    int* bsum, int* nb_cnt, int* eb_cnt,
                                                    int N) {
    __shared__ int part[256];
    __shared__ int nbh[MAXD];
    __shared__ int ebh[MAXD];
    const int t = threadIdx.x;
    if (t < MAXD) { nbh[t] = 0; ebh[t] = 0; }
    __syncthreads();
    const int base = blockIdx.x * SCAN_CHUNK + t * 4;
    int s = 0;
    #pragma unroll
    for (int i = 0; i < 4; ++i) {
        int gi = base + i;
        if (gi < N) {
            s += in_cnt[gi];
            int dg = deg[gi];
            int b = (dg < MAXD - 1) ? dg : (MAXD - 1);
            atomicAdd(&nbh[b], 1);
            if (dg > 0) atomicAdd(&ebh[b], dg);
        }
    }
    part[t] = s;
    __syncthreads();
    for (int off = 128; off > 0; off >>= 1) {
        if (t < off) part[t] += part[t + off];
        __syncthreads();
    }
    if (t == 0) bsum[blockIdx.x] = part[0];
    if (t < MAXD) {
        if (nbh[t] > 0) atomicAdd(&nb_cnt[t], nbh[t]);
        if (ebh[t] > 0) atomicAdd(&eb_cnt[t], ebh[t]);
    }
}

__global__ __launch_bounds__(256) void scanB_kernel(int* bsum, int nb,
                                                    const int* __restrict__ nb_cnt,
                                                    int* nb_cursor,
                                                    const int* __restrict__ eb_cnt,
                                                    int* eb_cursor, int* eb_base,
                                                    int* row_ptr, int N, int E) {
    __shared__ int part[256];
    const int t = threadIdx.x;
    int v = (t < nb) ? bsum[t] : 0;
    part[t] = v;
    __syncthreads();
    for (int off = 1; off < 256; off <<= 1) {
        int add = (t >= off) ? part[t - off] : 0;
        __syncthreads();
        part[t] += add;
        __syncthreads();
    }
    if (t < nb) bsum[t] = part[t] - v;   // exclusive
    if (t == 0) {
        int acc = 0;
        for (int b = 0; b < MAXD; ++b) { nb_cursor[b] = acc; acc += nb_cnt[b]; }
        acc = 0;
        for (int b = 0; b < MAXD; ++b) {
            eb_cursor[b] = acc; eb_base[b] = acc; acc += eb_cnt[b];
        }
        eb_base[MAXD] = E;
        row_ptr[N] = E;
    }
}

__global__ __launch_bounds__(256) void scanC_kernel(const int* __restrict__ in_cnt,
                                                    const int* __restrict__ bsum,
                                                    int* cursorN, int* row_ptr, int N) {
    __shared__ int part[256];
    const int t = threadIdx.x;
    const int base = blockIdx.x * SCAN_CHUNK + t * 4;
    int v[4] = {0, 0, 0, 0};
    #pragma unroll
    for (int i = 0; i < 4; ++i) if (base + i < N) v[i] = in_cnt[base + i];
    const int s = v[0] + v[1] + v[2] + v[3];
    part[t] = s;
    __syncthreads();
    for (int off = 1; off < 256; off <<= 1) {
        int add = (t >= off) ? part[t - off] : 0;
        __syncthreads();
        part[t] += add;
        __syncthreads();
    }
    int a = bsum[blockIdx.x] + part[t] - s;
    #pragma unroll
    for (int i = 0; i < 4; ++i) {
        if (base + i < N) { cursorN[base + i] = a; row_ptr[base + i] = a; }
        a += v[i];
    }
}

// fused scatter: blocks [0, nbN) node-bucket scatter; [nbN, nbN+nbE) edge scatter.
__global__ __launch_bounds__(256) void scatter_kernel(
    const int* __restrict__ ei, const float* __restrict__ ea, const int* __restrict__ deg,
    int* nb_cursor, int* node_list,
    int* cursorN, int* eb_cursor, int* src_csr, int* csr2bkt, float* ea_bkt,
    int N, int E, int nbN)
{
    __shared__ int h[MAXD];
    __shared__ int base[MAXD];
    const int t = threadIdx.x;
    if (t < MAXD) h[t] = 0;
    __syncthreads();

    if (blockIdx.x < nbN) {
        const int n = blockIdx.x * 256 + t;
        int b = 0, loc = 0;
        const bool valid = n < N;
        if (valid) {
            int dg = deg[n];
            b = (dg < MAXD - 1) ? dg : (MAXD - 1);
            loc = atomicAdd(&h[b], 1);
        }
        __syncthreads();
        if (t < MAXD) base[t] = (h[t] > 0) ? atomicAdd(&nb_cursor[t], h[t]) : 0;
        __syncthreads();
        if (valid) node_list[base[b] + loc] = n;
    } else {
        const int e = (blockIdx.x - nbN) * 256 + t;
        const bool valid = e < E;
        int s = 0, d = 0, b = 0, loc = 0;
        if (valid) {
            s = ei[e]; d = ei[E + e];
            int dg = deg[s];
            b = (dg < MAXD - 1) ? dg : (MAXD - 1);
            loc = atomicAdd(&h[b], 1);
        }
        __syncthreads();
        if (t < MAXD) base[t] = (h[t] > 0) ? atomicAdd(&eb_cursor[t], h[t]) : 0;
        __syncthreads();
        if (valid) {
            const int posz = base[b] + loc;
            const int pos = atomicAdd(&cursorN[d], 1);
            src_csr[pos] = s;
            csr2bkt[pos] = posz;
            const float4* p = (const float4*)(ea + (size_t)e * ECH);
            float4* o = (float4*)(ea_bkt + (size_t)posz * ECH);
            o[0] = p[0]; o[1] = p[1]; o[2] = p[2]; o[3] = p[3];
        }
    }
}

// ---------------- one-time: z-GEMM per timestep (fp16, nontemporal stores) ----------------
// 512-thread blocks, 32 groups x 4 edges: low per-thread state, 8-wave blocks.

__global__ __launch_bounds__(512) void zgemm_kernel(
    const float* __restrict__ ea_bkt, __half* __restrict__ zs,
    const int* __restrict__ eb_base, const float* __restrict__ Wmsg,
    int E, int ntiles)
{
    __shared__ float Ez[ECH][TILE_Z + 4];   // 8.25 KB
    __shared__ int ebase_s[MAXD + 1];

    const int t = threadIdx.x;
    const int bid = blockIdx.x;
    const int tt = bid / ntiles;
    const int i0 = (bid % ntiles) * TILE_Z;
    const float* Wt = Wmsg + (size_t)tt * MAXD * KD * IN;
    __half* zt = zs + (size_t)tt * E * IN;
    const int ntile = min(TILE_Z, E - i0);

    if (t <= MAXD) ebase_s[t] = eb_base[t];
    {
        const int e = t >> 2;
        const int j0 = (t & 3) * 4;
        const bool valid = e < ntile;
        const float4 z4 = make_float4(0.f, 0.f, 0.f, 0.f);
        float4 v = valid ? *(const float4*)(ea_bkt + (size_t)(i0 + e) * ECH + j0) : z4;
        Ez[j0 + 0][e] = v.x; Ez[j0 + 1][e] = v.y;
        Ez[j0 + 2][e] = v.z; Ez[j0 + 3][e] = v.w;
    }
    __syncthreads();

    const int eg4 = (t >> 4) * 4;   // 0..124
    const int cg4 = (t & 15) * 4;

    int b = 0;
    #pragma unroll
    for (int q = 1; q < MAXD; ++q) if (ebase_s[q] <= i0) b = q;

    for (; b < MAXD; ++b) {
        const int slo = max(ebase_s[b] - i0, 0);
        const int shi = min(ebase_s[b + 1] - i0, ntile);
        if (shi > slo) {
            const float* wp = Wt + ((size_t)b * KD + IN) * IN + cg4;

            float acc[4][4];
            #pragma unroll
            for (int e2 = 0; e2 < 4; ++e2)
                #pragma unroll
                for (int c = 0; c < 4; ++c) acc[e2][c] = 0.f;

            #pragma unroll
            for (int half = 0; half < 2; ++half) {
                float4 w[8];
                #pragma unroll
                for (int k = 0; k < 8; ++k)
                    w[k] = *(const float4*)(wp + (size_t)(half * 8 + k) * IN);
                #pragma unroll
                for (int k = 0; k < 8; ++k) {
                    const int kk = half * 8 + k;
                    const float4 m = *(const float4*)&Ez[kk][eg4];
                    const float me[4] = {m.x, m.y, m.z, m.w};
                    #pragma unroll
                    for (int e2 = 0; e2 < 4; ++e2) {
                        acc[e2][0] += me[e2] * w[k].x;
                        acc[e2][1] += me[e2] * w[k].y;
                        acc[e2][2] += me[e2] * w[k].z;
                        acc[e2][3] += me[e2] * w[k].w;
                    }
                }
            }

            #pragma unroll
            for (int e2 = 0; e2 < 4; ++e2) {
                const int el = eg4 + e2;
                if (el >= slo && el < shi) {
                    union { __half2 h[2]; unsigned long long u; } pk;
                    pk.h[0] = __floats2half2_rn(acc[e2][0], acc[e2][1]);
                    pk.h[1] = __floats2half2_rn(acc[e2][2], acc[e2][3]);
                    __builtin_nontemporal_store(pk.u,
                        (unsigned long long*)(zt + (size_t)(i0 + el) * IN + cg4));
                }
            }
        }
        if (ebase_s[b + 1] >= i0 + ntile) break;
    }
}

// ---------------- per-timestep: node transform y = Wx[b]^T x ----------------

__global__ __launch_bounds__(256) void y_kernel(
    const float* __restrict__ xin, float* __restrict__ y,
    const int* __restrict__ node_list, const int* __restrict__ deg,
    const float* __restrict__ Wt, int N)
{
    __shared__ float Ws[IN][IN];           // 16 KB
    __shared__ float Ms[IN][TILE_N + 4];   // 17.4 KB
    __shared__ int id_s[TILE_N];
    __shared__ int bkt_s[TILE_N];

    const int t = threadIdx.x;
    const int i0 = blockIdx.x * TILE_N;
    const int ntile = min(TILE_N, N - i0);

    {
        const int e = t >> 2;
        const bool valid = e < ntile;
        const int c0 = (t & 3) * 16;
        const float4 z4 = make_float4(0.f, 0.f, 0.f, 0.f);
        int node = valid ? node_list[i0 + e] : 0;
        const float* xp = xin + (size_t)node * IN + c0;
        #pragma unroll
        for (int i = 0; i < 16; i += 4) {
            float4 v = valid ? *(const float4*)(xp + i) : z4;
            Ms[c0 + i + 0][e] = v.x; Ms[c0 + i + 1][e] = v.y;
            Ms[c0 + i + 2][e] = v.z; Ms[c0 + i + 3][e] = v.w;
        }
        if (t < TILE_N) {
            if (t < ntile) {
                int id = node_list[i0 + t];
                id_s[t] = id;
                int dg = deg[id];
                bkt_s[t] = (dg < MAXD - 1) ? dg : (MAXD - 1);
            } else { id_s[t] = 0; bkt_s[t] = -1; }
        }
    }
    __syncthreads();

    const int b_first = bkt_s[0];
    const int b_last = bkt_s[ntile - 1];
    const int eg4 = (t >> 4) * 4;
    const int cg4 = (t & 15) * 4;

    for (int b = b_first; b <= b_last; ++b) {
        if (b != b_first) __syncthreads();
        {
            const float4* Wb = (const float4*)(Wt + (size_t)b * KD * IN);
            float4* Wsp = (float4*)Ws;
            #pragma unroll
            for (int q = 0; q < 4; ++q) Wsp[t + q * 256] = Wb[t + q * 256];
        }
        __syncthreads();

        float acc[4][4];
        #pragma unroll
        for (int e2 = 0; e2 < 4; ++e2)
            #pragma unroll
            for (int c = 0; c < 4; ++c) acc[e2][c] = 0.f;

        #pragma unroll 8
        for (int k = 0; k < IN; ++k) {
            const float4 w = *(const float4*)&Ws[k][cg4];
            const float4 m = *(const float4*)&Ms[k][eg4];
            const float me[4] = {m.x, m.y, m.z, m.w};
            #pragma unroll
            for (int e2 = 0; e2 < 4; ++e2) {
                acc[e2][0] += me[e2] * w.x;
                acc[e2][1] += me[e2] * w.y;
                acc[e2][2] += me[e2] * w.z;
                acc[e2][3] += me[e2] * w.w;
            }
        }

        #pragma unroll
        for (int e2 = 0; e2 < 4; ++e2) {
            const int el = eg4 + e2;
            if (el < ntile && bkt_s[el] == b) {
                const size_t o = (size_t)id_s[el] * IN + cg4;
                *(float4*)(y + o) = make_float4(acc[e2][0], acc[e2][1],
                                                acc[e2][2], acc[e2][3]);
            }
        }
    }
}

// ---------------- per-timestep: lean aggregation (no W, no LDS) ----------------

__global__ __launch_bounds__(AGG_BLOCK) void aggS_kernel(
    const float* __restrict__ y, float* __restrict__ out,
    const int* __restrict__ row_ptr, const int* __restrict__ src_csr,
    const int* __restrict__ csr2bkt, const __half* __restrict__ zt, int N)
{
    const int t = threadIdx.x;
    const int lane = t & 63;
    const int grp = lane >> 4;
    const int gl = lane & 15;
    const int c0 = gl * 4;
    const int d = blockIdx.x * AGG_DPB + (t >> 6) * 4 + grp;
    if (d >= N) return;
    const int lane0 = grp * 16;

    const int p0 = row_ptr[d];
    const int p1 = row_ptr[d + 1];

    float4 acc = make_float4(0.f, 0.f, 0.f, 0.f);

    for (int p = p0; p < p1; p += 8) {
        const int cnt = min(8, p1 - p);
        const int mi = p + (gl & 7);
        int s_r = 0, z_r = 0;
        if (mi < p1) { s_r = src_csr[mi]; z_r = csr2bkt[mi]; }

        float4 yv[8];
        uint2 zu[8];
        #pragma unroll
        for (int i = 0; i < 8; ++i) {
            int si = __shfl(s_r, lane0 + i);
            int zi = __shfl(z_r, lane0 + i);
            if (i < cnt) {
                yv[i] = *(const float4*)(y + (size_t)si * IN + c0);
                zu[i] = *(const uint2*)(zt + (size_t)zi * IN + c0);
            }
        }
        #pragma unroll
        for (int i = 0; i < 8; ++i) {
            if (i < cnt) {
                const __half2* zh = (const __half2*)&zu[i];
                float2 z01 = __half22float2(zh[0]);
                float2 z23 = __half22float2(zh[1]);
                acc.x += sigmoidf(yv[i].x + z01.x);
                acc.y += sigmoidf(yv[i].y + z01.y);
                acc.z += sigmoidf(yv[i].z + z23.x);
                acc.w += sigmoidf(yv[i].w + z23.y);
            }
        }
    }

    const float4 yd = *(const float4*)(y + (size_t)d * IN + c0);
    float4 r = make_float4(sigmoidf(yd.x) + acc.x, sigmoidf(yd.y) + acc.y,
                           sigmoidf(yd.z) + acc.z, sigmoidf(yd.w) + acc.w);
    *(float4*)(out + (size_t)d * IN + c0) = r;
}

// ---------------- readout + pooling ----------------

__global__ __launch_bounds__(256) void readout_kernel(
    const float* __restrict__ x, const float* __restrict__ Wr,
    const int* __restrict__ batch, float* __restrict__ pooled, int N)
{
    __shared__ float Wr_s[TSTEPS][10][IN];
    __shared__ float pool_s[64 * 10];
    const int t = threadIdx.x;
    for (int idx = t; idx < TSTEPS * IN * 10; idx += 256) {
        int tt = idx / (IN * 10);
        int r = idx % (IN * 10);
        int k = r / 10;
        int j = r % 10;
        Wr_s[tt][j][k] = Wr[idx];
    }
    for (int idx = t; idx < 64 * 10; idx += 256) pool_s[idx] = 0.f;
    __syncthreads();

    const int n = blockIdx.x * 256 + t;
    if (n < N) {
        float xr[IN];
        const float4* xp = (const float4*)(x + (size_t)n * IN);
        #pragma unroll
        for (int i = 0; i < IN / 4; ++i) ((float4*)xr)[i] = xp[i];
        float out10[10];
        #pragma unroll
        for (int j = 0; j < 10; ++j) out10[j] = 0.f;
        for (int tt = 0; tt < TSTEPS; ++tt) {
            float lg[10];
            #pragma unroll
            for (int j = 0; j < 10; ++j) {
                const float4* wp = (const float4*)Wr_s[tt][j];
                float s = 0.f;
                #pragma unroll
                for (int i = 0; i < IN / 4; ++i) {
                    float4 w = wp[i];
                    float4 xv = ((const float4*)xr)[i];
                    s += w.x * xv.x + w.y * xv.y + w.z * xv.z + w.w * xv.w;
                }
                lg[j] = s;
            }
            float mx = lg[0];
            #pragma unroll
            for (int j = 1; j < 10; ++j) mx = fmaxf(mx, lg[j]);
            float sum = 0.f;
            #pragma unroll
            for (int j = 0; j < 10; ++j) { lg[j] = __expf(lg[j] - mx); sum += lg[j]; }
            float inv = 1.f / sum;
            #pragma unroll
            for (int j = 0; j < 10; ++j) out10[j] += lg[j] * inv;
        }
        const int g = batch[n];
        #pragma unroll
        for (int j = 0; j < 10; ++j) atomicAdd(&pool_s[g * 10 + j], out10[j]);
    }
    __syncthreads();
    for (int idx = t; idx < 64 * 10; idx += 256) {
        float v = pool_s[idx];
        if (v != 0.f) atomicAdd(&pooled[idx], v);
    }
}

// ---------------- final MLP ----------------

__global__ __launch_bounds__(256) void mlp_kernel(
    const float* __restrict__ pooled,
    const float* __restrict__ fc1w, const float* __restrict__ fc1b,
    const float* __restrict__ fc2w, const float* __restrict__ fc2b,
    const float* __restrict__ fc3w, const float* __restrict__ fc3b,
    float* __restrict__ out, int G)
{
    __shared__ float p_s[64 * 10];
    __shared__ float h1[64 * 128];
    __shared__ float h2[64 * 64];
    const int t = threadIdx.x;
    for (int idx = t; idx < G * 10; idx += 256) p_s[idx] = pooled[idx];
    __syncthreads();
    for (int idx = t; idx < G * 128; idx += 256) {
        int g = idx >> 7, j = idx & 127;
        float s = fc1b[j];
        #pragma unroll
        for (int k = 0; k < 10; ++k) s += p_s[g * 10 + k] * fc1w[k * 128 + j];
        h1[idx] = (s > 0.f) ? s : 0.01f * s;
    }
    __syncthreads();
    for (int idx = t; idx < G * 64; idx += 256) {
        int g = idx >> 6, j = idx & 63;
        float s = fc2b[j];
        for (int k = 0; k < 128; ++k) s += h1[(g << 7) + k] * fc2w[(k << 6) + j];
        h2[idx] = (s > 0.f) ? s : 0.01f * s;
    }
    __syncthreads();
    if (t < G) {
        float s = fc3b[0];
        for (int k = 0; k < 64; ++k) s += h2[(t << 6) + k] * fc3w[k];
        out[t] = (s > 0.f) ? s : 0.01f * s;
    }
}

// ---------------- launch ----------------

extern "C" void kernel_launch(void* const* d_in, const int* in_sizes, int n_in,
                              void* d_out, int out_size, void* d_ws, size_t ws_size,
                              hipStream_t stream)
{
    const float* x     = (const float*)d_in[0];
    const float* ea    = (const float*)d_in[1];
    const float* Wmsg  = (const float*)d_in[2];
    const float* Wread = (const float*)d_in[3];
    const float* fc1w  = (const float*)d_in[4];
    const float* fc1b  = (const float*)d_in[5];
    const float* fc2w  = (const float*)d_in[6];
    const float* fc2b  = (const float*)d_in[7];
    const float* fc3w  = (const float*)d_in[8];
    const float* fc3b  = (const float*)d_in[9];
    const int* ei      = (const int*)d_in[10];
    const int* batch   = (const int*)d_in[11];

    const int N = in_sizes[0] / IN;
    const int E = in_sizes[10] / 2;
    const int nscan = (N + SCAN_CHUNK - 1) / SCAN_CHUNK;
    const int ntilesZ = (E + TILE_Z - 1) / TILE_Z;

    char* ws = (char*)d_ws;
    size_t off = 0;
    auto take = [&](size_t bytes) {
        char* p = ws + off;
        off = (off + bytes + 255) & ~(size_t)255;
        return p;
    };
    // zero-region: [meta | pooled | deg | in_cnt] — single memset per launch
    int* meta      = (int*)take(512);
    float* pooled  = (float*)take(64 * 10 * 4);
    int* deg       = (int*)take((size_t)N * 4);
    int* in_cnt    = (int*)take((size_t)N * 4);
    const size_t zero_bytes = (size_t)((char*)in_cnt - (char*)meta) + (size_t)N * 4;
    int* bsum      = (int*)take((size_t)nscan * 4);
    int* node_list = (int*)take((size_t)N * 4);
    int* cursorN   = (int*)take((size_t)N * 4);
    int* row_ptr   = (int*)take((size_t)(N + 1) * 4);
    int* src_csr   = (int*)take((size_t)E * 4);
    int* csr2bkt   = (int*)take((size_t)E * 4);
    float* ea_bkt  = (float*)take((size_t)E * ECH * 4);
    __half* zs     = (__half*)take((size_t)TSTEPS * E * IN * 2);  // 82 MB fp16
    float* ybuf    = (float*)take((size_t)N * IN * 4);
    float* xbA     = (float*)take((size_t)N * IN * 4);
    float* xbB     = (float*)take((size_t)N * IN * 4);

    int* nb_cnt    = meta;        // [0..9]
    int* nb_cursor = meta + 16;   // [16..25]
    int* eb_cnt    = meta + 32;   // [32..41]
    int* eb_cursor = meta + 48;   // [48..57]
    int* eb_base   = meta + 64;   // [64..74]

    const int nbN = (N + 255) / 256;
    const int nbE = (E + 255) / 256;

    hipMemsetAsync(meta, 0, zero_bytes, stream);
    hist_kernel<<<nbE, 256, 0, stream>>>(ei, deg, in_cnt, E);
    scanA_kernel<<<nscan, 256, 0, stream>>>(in_cnt, deg, bsum, nb_cnt, eb_cnt, N);
    scanB_kernel<<<1, 256, 0, stream>>>(bsum, nscan, nb_cnt, nb_cursor,
                                        eb_cnt, eb_cursor, eb_base, row_ptr, N, E);
    scanC_kernel<<<nscan, 256, 0, stream>>>(in_cnt, bsum, cursorN, row_ptr, N);
    scatter_kernel<<<nbN + nbE, 256, 0, stream>>>(ei, ea, deg, nb_cursor, node_list,
                                                  cursorN, eb_cursor, src_csr, csr2bkt,
                                                  ea_bkt, N, E, nbN);
    zgemm_kernel<<<TSTEPS * ntilesZ, 512, 0, stream>>>(ea_bkt, zs, eb_base, Wmsg,
                                                       E, ntilesZ);

    const int nblkY = (N + TILE_N - 1) / TILE_N;
    const int nblkA = (N + AGG_DPB - 1) / AGG_DPB;
    const float* xi = x;
    float* bufs[2] = {xbA, xbB};
    for (int tt = 0; tt < TSTEPS; ++tt) {
        const float* Wt = Wmsg + (size_t)tt * MAXD * KD * IN;
        float* xo = bufs[tt & 1];
        y_kernel<<<nblkY, 256, 0, stream>>>(xi, ybuf, node_list, deg, Wt, N);
        aggS_kernel<<<nblkA, AGG_BLOCK, 0, stream>>>(ybuf, xo, row_ptr, src_csr,
                                                     csr2bkt,
                                                     zs + (size_t)tt * E * IN, N);
        xi = xo;
    }

    readout_kernel<<<nbN, 256, 0, stream>>>(xi, Wread, batch, pooled, N);
    mlp_kernel<<<1, 256, 0, stream>>>(pooled, fc1w, fc1b, fc2w, fc2b, fc3w, fc3b,
                                      (float*)d_out, out_size);
}

// Round 21
// 290.269 us; speedup vs baseline: 1.0411x; 1.0411x over previous
//
#include <hip/hip_runtime.h>
#include <hip/hip_fp16.h>

#define MAXD 10
#define TSTEPS 4
#define KD 80      // IN + EC
#define IN 64
#define ECH 16
#define TILE_N 64   // nodes per block in y_kernel
#define TILE_Z 128  // edges per block in zgemm
#define SCAN_CHUNK 1024

#define AGG_BLOCK 256
#define AGG_DPB (AGG_BLOCK / 16)   // 16 dsts per block (one per 16-lane group)

__device__ __forceinline__ float sigmoidf(float v) {
    return 1.0f / (1.0f + __expf(-v));
}

// ---------------- preprocessing ----------------
// deg[] counts out-edges EXCLUDING self loop; bucket = min(deg, MAXD-1).

__global__ __launch_bounds__(256) void hist_kernel(const int* __restrict__ ei,
                                                   int* deg, int* in_cnt, int E) {
    int e = blockIdx.x * 256 + threadIdx.x;
    if (e < E) {
        atomicAdd(&deg[ei[e]], 1);
        atomicAdd(&in_cnt[ei[E + e]], 1);
    }
}

// scanA: block partial sums of in_cnt; fused node-bucket AND edge-bucket
// histograms (edge count per bucket = sum of deg over nodes in that bucket).
__global__ __launch_bounds__(256) void scanA_kernel(const int* __restrict__ in_cnt,
                                                    const int* __restrict__ deg,
                                                    int* bsum, int* nb_cnt, int* eb_cnt,
                                                    int N) {
    __shared__ int part[256];
    __shared__ int nbh[MAXD];
    __shared__ int ebh[MAXD];
    const int t = threadIdx.x;
    if (t < MAXD) { nbh[t] = 0; ebh[t] = 0; }
    __syncthreads();
    const int base = blockIdx.x * SCAN_CHUNK + t * 4;
    int s = 0;
    #pragma unroll
    for (int i = 0; i < 4; ++i) {
        int gi = base + i;
        if (gi < N) {
            s += in_cnt[gi];
            int dg = deg[gi];
            int b = (dg < MAXD - 1) ? dg : (MAXD - 1);
            atomicAdd(&nbh[b], 1);
            if (dg > 0) atomicAdd(&ebh[b], dg);
        }
    }
    part[t] = s;
    __syncthreads();
    for (int off = 128; off > 0; off >>= 1) {
        if (t < off) part[t] += part[t + off];
        __syncthreads();
    }
    if (t == 0) bsum[blockIdx.x] = part[0];
    if (t < MAXD) {
        if (nbh[t] > 0) atomicAdd(&nb_cnt[t], nbh[t]);
        if (ebh[t] > 0) atomicAdd(&eb_cnt[t], ebh[t]);
    }
}

__global__ __launch_bounds__(256) void scanB_kernel(int* bsum, int nb,
                                                    const int* __restrict__ nb_cnt,
                                                    int* nb_cursor,
                                                    const int* __restrict__ eb_cnt,
                                                    int* eb_cursor, int* eb_base,
                                                    int* row_ptr, int N, int E) {
    __shared__ int part[256];
    const int t = threadIdx.x;
    int v = (t < nb) ? bsum[t] : 0;
    part[t] = v;
    __syncthreads();
    for (int off = 1; off < 256; off <<= 1) {
        int add = (t >= off) ? part[t - off] : 0;
        __syncthreads();
        part[t] += add;
        __syncthreads();
    }
    if (t < nb) bsum[t] = part[t] - v;   // exclusive
    if (t == 0) {
        int acc = 0;
        for (int b = 0; b < MAXD; ++b) { nb_cursor[b] = acc; acc += nb_cnt[b]; }
        acc = 0;
        for (int b = 0; b < MAXD; ++b) {
            eb_cursor[b] = acc; eb_base[b] = acc; acc += eb_cnt[b];
        }
        eb_base[MAXD] = E;
        row_ptr[N] = E;
    }
}

__global__ __launch_bounds__(256) void scanC_kernel(const int* __restrict__ in_cnt,
                                                    const int* __restrict__ bsum,
                                                    int* cursorN, int* row_ptr, int N) {
    __shared__ int part[256];
    const int t = threadIdx.x;
    const int base = blockIdx.x * SCAN_CHUNK + t * 4;
    int v[4] = {0, 0, 0, 0};
    #pragma unroll
    for (int i = 0; i < 4; ++i) if (base + i < N) v[i] = in_cnt[base + i];
    const int s = v[0] + v[1] + v[2] + v[3];
    part[t] = s;
    __syncthreads();
    for (int off = 1; off < 256; off <<= 1) {
        int add = (t >= off) ? part[t - off] : 0;
        __syncthreads();
        part[t] += add;
        __syncthreads();
    }
    int a = bsum[blockIdx.x] + part[t] - s;
    #pragma unroll
    for (int i = 0; i < 4; ++i) {
        if (base + i < N) { cursorN[base + i] = a; row_ptr[base + i] = a; }
        a += v[i];
    }
}

// fused scatter: blocks [0, nbN) node-bucket scatter; [nbN, nbN+nbE) edge scatter.
__global__ __launch_bounds__(256) void scatter_kernel(
    const int* __restrict__ ei, const float* __restrict__ ea, const int* __restrict__ deg,
    int* nb_cursor, int* node_list,
    int* cursorN, int* eb_cursor, int* src_csr, int* csr2bkt, float* ea_bkt,
    int N, int E, int nbN)
{
    __shared__ int h[MAXD];
    __shared__ int base[MAXD];
    const int t = threadIdx.x;
    if (t < MAXD) h[t] = 0;
    __syncthreads();

    if (blockIdx.x < nbN) {
        const int n = blockIdx.x * 256 + t;
        int b = 0, loc = 0;
        const bool valid = n < N;
        if (valid) {
            int dg = deg[n];
            b = (dg < MAXD - 1) ? dg : (MAXD - 1);
            loc = atomicAdd(&h[b], 1);
        }
        __syncthreads();
        if (t < MAXD) base[t] = (h[t] > 0) ? atomicAdd(&nb_cursor[t], h[t]) : 0;
        __syncthreads();
        if (valid) node_list[base[b] + loc] = n;
    } else {
        const int e = (blockIdx.x - nbN) * 256 + t;
        const bool valid = e < E;
        int s = 0, d = 0, b = 0, loc = 0;
        if (valid) {
            s = ei[e]; d = ei[E + e];
            int dg = deg[s];
            b = (dg < MAXD - 1) ? dg : (MAXD - 1);
            loc = atomicAdd(&h[b], 1);
        }
        __syncthreads();
        if (t < MAXD) base[t] = (h[t] > 0) ? atomicAdd(&eb_cursor[t], h[t]) : 0;
        __syncthreads();
        if (valid) {
            const int posz = base[b] + loc;
            const int pos = atomicAdd(&cursorN[d], 1);
            src_csr[pos] = s;
            csr2bkt[pos] = posz;
            const float4* p = (const float4*)(ea + (size_t)e * ECH);
            float4* o = (float4*)(ea_bkt + (size_t)posz * ECH);
            o[0] = p[0]; o[1] = p[1]; o[2] = p[2]; o[3] = p[3];
        }
    }
}

// ---------------- one-time: z-GEMM per timestep (fp16, nontemporal stores) ----------------
// W slice loaded in two 8-row halves; R18 configuration (best measured).

__global__ __launch_bounds__(256) void zgemm_kernel(
    const float* __restrict__ ea_bkt, __half* __restrict__ zs,
    const int* __restrict__ eb_base, const float* __restrict__ Wmsg,
    int E, int ntiles)
{
    __shared__ float Ez[ECH][TILE_Z + 4];   // 8.25 KB
    __shared__ int ebase_s[MAXD + 1];

    const int t = threadIdx.x;
    const int bid = blockIdx.x;
    const int tt = bid / ntiles;
    const int i0 = (bid % ntiles) * TILE_Z;
    const float* Wt = Wmsg + (size_t)tt * MAXD * KD * IN;
    __half* zt = zs + (size_t)tt * E * IN;
    const int ntile = min(TILE_Z, E - i0);

    if (t <= MAXD) ebase_s[t] = eb_base[t];
    {
        const int e = t >> 1;
        const int j0 = (t & 1) * 8;
        const bool valid = e < ntile;
        const float4 z4 = make_float4(0.f, 0.f, 0.f, 0.f);
        const float* ep = ea_bkt + (size_t)(i0 + e) * ECH + j0;
        #pragma unroll
        for (int i = 0; i < 8; i += 4) {
            float4 v = valid ? *(const float4*)(ep + i) : z4;
            Ez[j0 + i + 0][e] = v.x; Ez[j0 + i + 1][e] = v.y;
            Ez[j0 + i + 2][e] = v.z; Ez[j0 + i + 3][e] = v.w;
        }
    }
    __syncthreads();

    const int eg8 = (t >> 4) * 8;
    const int cg4 = (t & 15) * 4;

    int b = 0;
    #pragma unroll
    for (int q = 1; q < MAXD; ++q) if (ebase_s[q] <= i0) b = q;

    for (; b < MAXD; ++b) {
        const int slo = max(ebase_s[b] - i0, 0);
        const int shi = min(ebase_s[b + 1] - i0, ntile);
        if (shi > slo) {
            const float* wp = Wt + ((size_t)b * KD + IN) * IN + cg4;

            float acc[8][4];
            #pragma unroll
            for (int e2 = 0; e2 < 8; ++e2)
                #pragma unroll
                for (int c = 0; c < 4; ++c) acc[e2][c] = 0.f;

            #pragma unroll
            for (int half = 0; half < 2; ++half) {
                float4 w[8];
                #pragma unroll
                for (int k = 0; k < 8; ++k)
                    w[k] = *(const float4*)(wp + (size_t)(half * 8 + k) * IN);
                #pragma unroll
                for (int k = 0; k < 8; ++k) {
                    const int kk = half * 8 + k;
                    const float4 m0 = *(const float4*)&Ez[kk][eg8];
                    const float4 m1 = *(const float4*)&Ez[kk][eg8 + 4];
                    const float me[8] = {m0.x, m0.y, m0.z, m0.w, m1.x, m1.y, m1.z, m1.w};
                    #pragma unroll
                    for (int e2 = 0; e2 < 8; ++e2) {
                        acc[e2][0] += me[e2] * w[k].x;
                        acc[e2][1] += me[e2] * w[k].y;
                        acc[e2][2] += me[e2] * w[k].z;
                        acc[e2][3] += me[e2] * w[k].w;
                    }
                }
            }

            #pragma unroll
            for (int e2 = 0; e2 < 8; ++e2) {
                const int el = eg8 + e2;
                if (el >= slo && el < shi) {
                    union { __half2 h[2]; unsigned long long u; } pk;
                    pk.h[0] = __floats2half2_rn(acc[e2][0], acc[e2][1]);
                    pk.h[1] = __floats2half2_rn(acc[e2][2], acc[e2][3]);
                    __builtin_nontemporal_store(pk.u,
                        (unsigned long long*)(zt + (size_t)(i0 + el) * IN + cg4));
                }
            }
        }
        if (ebase_s[b + 1] >= i0 + ntile) break;
    }
}

// ---------------- per-timestep: node transform y = Wx[b]^T x ----------------

__global__ __launch_bounds__(256) void y_kernel(
    const float* __restrict__ xin, float* __restrict__ y,
    const int* __restrict__ node_list, const int* __restrict__ deg,
    const float* __restrict__ Wt, int N)
{
    __shared__ float Ws[IN][IN];           // 16 KB
    __shared__ float Ms[IN][TILE_N + 4];   // 17.4 KB
    __shared__ int id_s[TILE_N];
    __shared__ int bkt_s[TILE_N];

    const int t = threadIdx.x;
    const int i0 = blockIdx.x * TILE_N;
    const int ntile = min(TILE_N, N - i0);

    {
        const int e = t >> 2;
        const bool valid = e < ntile;
        const int c0 = (t & 3) * 16;
        const float4 z4 = make_float4(0.f, 0.f, 0.f, 0.f);
        int node = valid ? node_list[i0 + e] : 0;
        const float* xp = xin + (size_t)node * IN + c0;
        #pragma unroll
        for (int i = 0; i < 16; i += 4) {
            float4 v = valid ? *(const float4*)(xp + i) : z4;
            Ms[c0 + i + 0][e] = v.x; Ms[c0 + i + 1][e] = v.y;
            Ms[c0 + i + 2][e] = v.z; Ms[c0 + i + 3][e] = v.w;
        }
        if (t < TILE_N) {
            if (t < ntile) {
                int id = node_list[i0 + t];
                id_s[t] = id;
                int dg = deg[id];
                bkt_s[t] = (dg < MAXD - 1) ? dg : (MAXD - 1);
            } else { id_s[t] = 0; bkt_s[t] = -1; }
        }
    }
    __syncthreads();

    const int b_first = bkt_s[0];
    const int b_last = bkt_s[ntile - 1];
    const int eg4 = (t >> 4) * 4;
    const int cg4 = (t & 15) * 4;

    for (int b = b_first; b <= b_last; ++b) {
        if (b != b_first) __syncthreads();
        {
            const float4* Wb = (const float4*)(Wt + (size_t)b * KD * IN);
            float4* Wsp = (float4*)Ws;
            #pragma unroll
            for (int q = 0; q < 4; ++q) Wsp[t + q * 256] = Wb[t + q * 256];
        }
        __syncthreads();

        float acc[4][4];
        #pragma unroll
        for (int e2 = 0; e2 < 4; ++e2)
            #pragma unroll
            for (int c = 0; c < 4; ++c) acc[e2][c] = 0.f;

        #pragma unroll 8
        for (int k = 0; k < IN; ++k) {
            const float4 w = *(const float4*)&Ws[k][cg4];
            const float4 m = *(const float4*)&Ms[k][eg4];
            const float me[4] = {m.x, m.y, m.z, m.w};
            #pragma unroll
            for (int e2 = 0; e2 < 4; ++e2) {
                acc[e2][0] += me[e2] * w.x;
                acc[e2][1] += me[e2] * w.y;
                acc[e2][2] += me[e2] * w.z;
                acc[e2][3] += me[e2] * w.w;
            }
        }

        #pragma unroll
        for (int e2 = 0; e2 < 4; ++e2) {
            const int el = eg4 + e2;
            if (el < ntile && bkt_s[el] == b) {
                const size_t o = (size_t)id_s[el] * IN + cg4;
                *(float4*)(y + o) = make_float4(acc[e2][0], acc[e2][1],
                                                acc[e2][2], acc[e2][3]);
            }
        }
    }
}

// ---------------- per-timestep: lean aggregation (no W, no LDS) ----------------
// zs read once -> nontemporal loads (keep L2 for reused y rows).

__global__ __launch_bounds__(AGG_BLOCK) void aggS_kernel(
    const float* __restrict__ y, float* __restrict__ out,
    const int* __restrict__ row_ptr, const int* __restrict__ src_csr,
    const int* __restrict__ csr2bkt, const __half* __restrict__ zt, int N)
{
    const int t = threadIdx.x;
    const int lane = t & 63;
    const int grp = lane >> 4;
    const int gl = lane & 15;
    const int c0 = gl * 4;
    const int d = blockIdx.x * AGG_DPB + (t >> 6) * 4 + grp;
    if (d >= N) return;
    const int lane0 = grp * 16;

    const int p0 = row_ptr[d];
    const int p1 = row_ptr[d + 1];

    float4 acc = make_float4(0.f, 0.f, 0.f, 0.f);

    for (int p = p0; p < p1; p += 8) {
        const int cnt = min(8, p1 - p);
        const int mi = p + (gl & 7);
        int s_r = 0, z_r = 0;
        if (mi < p1) { s_r = src_csr[mi]; z_r = csr2bkt[mi]; }

        float4 yv[8];
        unsigned long long zu[8];
        #pragma unroll
        for (int i = 0; i < 8; ++i) {
            int si = __shfl(s_r, lane0 + i);
            int zi = __shfl(z_r, lane0 + i);
            if (i < cnt) {
                yv[i] = *(const float4*)(y + (size_t)si * IN + c0);
                zu[i] = __builtin_nontemporal_load(
                    (const unsigned long long*)(zt + (size_t)zi * IN + c0));
            }
        }
        #pragma unroll
        for (int i = 0; i < 8; ++i) {
            if (i < cnt) {
                const __half2* zh = (const __half2*)&zu[i];
                float2 z01 = __half22float2(zh[0]);
                float2 z23 = __half22float2(zh[1]);
                acc.x += sigmoidf(yv[i].x + z01.x);
                acc.y += sigmoidf(yv[i].y + z01.y);
                acc.z += sigmoidf(yv[i].z + z23.x);
                acc.w += sigmoidf(yv[i].w + z23.y);
            }
        }
    }

    const float4 yd = *(const float4*)(y + (size_t)d * IN + c0);
    float4 r = make_float4(sigmoidf(yd.x) + acc.x, sigmoidf(yd.y) + acc.y,
                           sigmoidf(yd.z) + acc.z, sigmoidf(yd.w) + acc.w);
    *(float4*)(out + (size_t)d * IN + c0) = r;
}

// ---------------- readout + pooling ----------------

__global__ __launch_bounds__(256) void readout_kernel(
    const float* __restrict__ x, const float* __restrict__ Wr,
    const int* __restrict__ batch, float* __restrict__ pooled, int N)
{
    __shared__ float Wr_s[TSTEPS][10][IN];
    __shared__ float pool_s[64 * 10];
    const int t = threadIdx.x;
    for (int idx = t; idx < TSTEPS * IN * 10; idx += 256) {
        int tt = idx / (IN * 10);
        int r = idx % (IN * 10);
        int k = r / 10;
        int j = r % 10;
        Wr_s[tt][j][k] = Wr[idx];
    }
    for (int idx = t; idx < 64 * 10; idx += 256) pool_s[idx] = 0.f;
    __syncthreads();

    const int n = blockIdx.x * 256 + t;
    if (n < N) {
        float xr[IN];
        const float4* xp = (const float4*)(x + (size_t)n * IN);
        #pragma unroll
        for (int i = 0; i < IN / 4; ++i) ((float4*)xr)[i] = xp[i];
        float out10[10];
        #pragma unroll
        for (int j = 0; j < 10; ++j) out10[j] = 0.f;
        for (int tt = 0; tt < TSTEPS; ++tt) {
            float lg[10];
            #pragma unroll
            for (int j = 0; j < 10; ++j) {
                const float4* wp = (const float4*)Wr_s[tt][j];
                float s = 0.f;
                #pragma unroll
                for (int i = 0; i < IN / 4; ++i) {
                    float4 w = wp[i];
                    float4 xv = ((const float4*)xr)[i];
                    s += w.x * xv.x + w.y * xv.y + w.z * xv.z + w.w * xv.w;
                }
                lg[j] = s;
            }
            float mx = lg[0];
            #pragma unroll
            for (int j = 1; j < 10; ++j) mx = fmaxf(mx, lg[j]);
            float sum = 0.f;
            #pragma unroll
            for (int j = 0; j < 10; ++j) { lg[j] = __expf(lg[j] - mx); sum += lg[j]; }
            float inv = 1.f / sum;
            #pragma unroll
            for (int j = 0; j < 10; ++j) out10[j] += lg[j] * inv;
        }
        const int g = batch[n];
        #pragma unroll
        for (int j = 0; j < 10; ++j) atomicAdd(&pool_s[g * 10 + j], out10[j]);
    }
    __syncthreads();
    for (int idx = t; idx < 64 * 10; idx += 256) {
        float v = pool_s[idx];
        if (v != 0.f) atomicAdd(&pooled[idx], v);
    }
}

// ---------------- final MLP ----------------

__global__ __launch_bounds__(256) void mlp_kernel(
    const float* __restrict__ pooled,
    const float* __restrict__ fc1w, const float* __restrict__ fc1b,
    const float* __restrict__ fc2w, const float* __restrict__ fc2b,
    const float* __restrict__ fc3w, const float* __restrict__ fc3b,
    float* __restrict__ out, int G)
{
    __shared__ float p_s[64 * 10];
    __shared__ float h1[64 * 128];
    __shared__ float h2[64 * 64];
    const int t = threadIdx.x;
    for (int idx = t; idx < G * 10; idx += 256) p_s[idx] = pooled[idx];
    __syncthreads();
    for (int idx = t; idx < G * 128; idx += 256) {
        int g = idx >> 7, j = idx & 127;
        float s = fc1b[j];
        #pragma unroll
        for (int k = 0; k < 10; ++k) s += p_s[g * 10 + k] * fc1w[k * 128 + j];
        h1[idx] = (s > 0.f) ? s : 0.01f * s;
    }
    __syncthreads();
    for (int idx = t; idx < G * 64; idx += 256) {
        int g = idx >> 6, j = idx & 63;
        float s = fc2b[j];
        for (int k = 0; k < 128; ++k) s += h1[(g << 7) + k] * fc2w[(k << 6) + j];
        h2[idx] = (s > 0.f) ? s : 0.01f * s;
    }
    __syncthreads();
    if (t < G) {
        float s = fc3b[0];
        for (int k = 0; k < 64; ++k) s += h2[(t << 6) + k] * fc3w[k];
        out[t] = (s > 0.f) ? s : 0.01f * s;
    }
}

// ---------------- launch ----------------

extern "C" void kernel_launch(void* const* d_in, const int* in_sizes, int n_in,
                              void* d_out, int out_size, void* d_ws, size_t ws_size,
                              hipStream_t stream)
{
    const float* x     = (const float*)d_in[0];
    const float* ea    = (const float*)d_in[1];
    const float* Wmsg  = (const float*)d_in[2];
    const float* Wread = (const float*)d_in[3];
    const float* fc1w  = (const float*)d_in[4];
    const float* fc1b  = (const float*)d_in[5];
    const float* fc2w  = (const float*)d_in[6];
    const float* fc2b  = (const float*)d_in[7];
    const float* fc3w  = (const float*)d_in[8];
    const float* fc3b  = (const float*)d_in[9];
    const int* ei      = (const int*)d_in[10];
    const int* batch   = (const int*)d_in[11];

    const int N = in_sizes[0] / IN;
    const int E = in_sizes[10] / 2;
    const int nscan = (N + SCAN_CHUNK - 1) / SCAN_CHUNK;
    const int ntilesZ = (E + TILE_Z - 1) / TILE_Z;

    char* ws = (char*)d_ws;
    size_t off = 0;
    auto take = [&](size_t bytes) {
        char* p = ws + off;
        off = (off + bytes + 255) & ~(size_t)255;
        return p;
    };
    // zero-region: [meta | pooled | deg | in_cnt] — single memset per launch
    int* meta      = (int*)take(512);
    float* pooled  = (float*)take(64 * 10 * 4);
    int* deg       = (int*)take((size_t)N * 4);
    int* in_cnt    = (int*)take((size_t)N * 4);
    const size_t zero_bytes = (size_t)((char*)in_cnt - (char*)meta) + (size_t)N * 4;
    int* bsum      = (int*)take((size_t)nscan * 4);
    int* node_list = (int*)take((size_t)N * 4);
    int* cursorN   = (int*)take((size_t)N * 4);
    int* row_ptr   = (int*)take((size_t)(N + 1) * 4);
    int* src_csr   = (int*)take((size_t)E * 4);
    int* csr2bkt   = (int*)take((size_t)E * 4);
    float* ea_bkt  = (float*)take((size_t)E * ECH * 4);
    __half* zs     = (__half*)take((size_t)TSTEPS * E * IN * 2);  // 82 MB fp16
    float* ybuf    = (float*)take((size_t)N * IN * 4);
    float* xbA     = (float*)take((size_t)N * IN * 4);
    float* xbB     = (float*)take((size_t)N * IN * 4);

    int* nb_cnt    = meta;        // [0..9]
    int* nb_cursor = meta + 16;   // [16..25]
    int* eb_cnt    = meta + 32;   // [32..41]
    int* eb_cursor = meta + 48;   // [48..57]
    int* eb_base   = meta + 64;   // [64..74]

    const int nbN = (N + 255) / 256;
    const int nbE = (E + 255) / 256;

    hipMemsetAsync(meta, 0, zero_bytes, stream);
    hist_kernel<<<nbE, 256, 0, stream>>>(ei, deg, in_cnt, E);
    scanA_kernel<<<nscan, 256, 0, stream>>>(in_cnt, deg, bsum, nb_cnt, eb_cnt, N);
    scanB_kernel<<<1, 256, 0, stream>>>(bsum, nscan, nb_cnt, nb_cursor,
                                        eb_cnt, eb_cursor, eb_base, row_ptr, N, E);
    scanC_kernel<<<nscan, 256, 0, stream>>>(in_cnt, bsum, cursorN, row_ptr, N);
    scatter_kernel<<<nbN + nbE, 256, 0, stream>>>(ei, ea, deg, nb_cursor, node_list,
                                                  cursorN, eb_cursor, src_csr, csr2bkt,
                                                  ea_bkt, N, E, nbN);
    zgemm_kernel<<<TSTEPS * ntilesZ, 256, 0, stream>>>(ea_bkt, zs, eb_base, Wmsg,
                                                       E, ntilesZ);

    const int nblkY = (N + TILE_N - 1) / TILE_N;
    const int nblkA = (N + AGG_DPB - 1) / AGG_DPB;
    const float* xi = x;
    float* bufs[2] = {xbA, xbB};
    for (int tt = 0; tt < TSTEPS; ++tt) {
        const float* Wt = Wmsg + (size_t)tt * MAXD * KD * IN;
        float* xo = bufs[tt & 1];
        y_kernel<<<nblkY, 256, 0, stream>>>(xi, ybuf, node_list, deg, Wt, N);
        aggS_kernel<<<nblkA, AGG_BLOCK, 0, stream>>>(ybuf, xo, row_ptr, src_csr,
                                                     csr2bkt,
                                                     zs + (size_t)tt * E * IN, N);
        xi = xo;
    }

    readout_kernel<<<nbN, 256, 0, stream>>>(xi, Wread, batch, pooled, N);
    mlp_kernel<<<1, 256, 0, stream>>>(pooled, fc1w, fc1b, fc2w, fc2b, fc3w, fc3b,
                                      (float*)d_out, out_size);
}

// Round 22
// 286.095 us; speedup vs baseline: 1.0563x; 1.0146x over previous
//
#include <hip/hip_runtime.h>
#include <hip/hip_fp16.h>

#define MAXD 10
#define TSTEPS 4
#define KD 80      // IN + EC
#define IN 64
#define ECH 16
#define TILE_N 64   // nodes per block in y path
#define TILE_Z 128  // edges per block in zgemm path
#define SCAN_CHUNK 1024

#define AGG_BLOCK 256
#define AGG_DPB (AGG_BLOCK / 16)   // 16 dsts per block (one per 16-lane group)

__device__ __forceinline__ float sigmoidf(float v) {
    return 1.0f / (1.0f + __expf(-v));
}

// ---------------- preprocessing ----------------
// deg[] counts out-edges EXCLUDING self loop; bucket = min(deg, MAXD-1).

__global__ __launch_bounds__(256) void hist_kernel(const int* __restrict__ ei,
                                                   int* deg, int* in_cnt, int E) {
    int e = blockIdx.x * 256 + threadIdx.x;
    if (e < E) {
        atomicAdd(&deg[ei[e]], 1);
        atomicAdd(&in_cnt[ei[E + e]], 1);
    }
}

// scanA: block partial sums of in_cnt; fused node-bucket AND edge-bucket
// histograms (edge count per bucket = sum of deg over nodes in that bucket).
__global__ __launch_bounds__(256) void scanA_kernel(const int* __restrict__ in_cnt,
                                                    const int* __restrict__ deg,
                                                    int* bsum, int* nb_cnt, int* eb_cnt,
                                                    int N) {
    __shared__ int part[256];
    __shared__ int nbh[MAXD];
    __shared__ int ebh[MAXD];
    const int t = threadIdx.x;
    if (t < MAXD) { nbh[t] = 0; ebh[t] = 0; }
    __syncthreads();
    const int base = blockIdx.x * SCAN_CHUNK + t * 4;
    int s = 0;
    #pragma unroll
    for (int i = 0; i < 4; ++i) {
        int gi = base + i;
        if (gi < N) {
            s += in_cnt[gi];
            int dg = deg[gi];
            int b = (dg < MAXD - 1) ? dg : (MAXD - 1);
            atomicAdd(&nbh[b], 1);
            if (dg > 0) atomicAdd(&ebh[b], dg);
        }
    }
    part[t] = s;
    __syncthreads();
    for (int off = 128; off > 0; off >>= 1) {
        if (t < off) part[t] += part[t + off];
        __syncthreads();
    }
    if (t == 0) bsum[blockIdx.x] = part[0];
    if (t < MAXD) {
        if (nbh[t] > 0) atomicAdd(&nb_cnt[t], nbh[t]);
        if (ebh[t] > 0) atomicAdd(&eb_cnt[t], ebh[t]);
    }
}

__global__ __launch_bounds__(256) void scanB_kernel(int* bsum, int nb,
                                                    const int* __restrict__ nb_cnt,
                                                    int* nb_cursor,
                                                    const int* __restrict__ eb_cnt,
                                                    int* eb_cursor, int* eb_base,
                                                    int* row_ptr, int N, int E) {
    __shared__ int part[256];
    const int t = threadIdx.x;
    int v = (t < nb) ? bsum[t] : 0;
    part[t] = v;
    __syncthreads();
    for (int off = 1; off < 256; off <<= 1) {
        int add = (t >= off) ? part[t - off] : 0;
        __syncthreads();
        part[t] += add;
        __syncthreads();
    }
    if (t < nb) bsum[t] = part[t] - v;   // exclusive
    if (t == 0) {
        int acc = 0;
        for (int b = 0; b < MAXD; ++b) { nb_cursor[b] = acc; acc += nb_cnt[b]; }
        acc = 0;
        for (int b = 0; b < MAXD; ++b) {
            eb_cursor[b] = acc; eb_base[b] = acc; acc += eb_cnt[b];
        }
        eb_base[MAXD] = E;
        row_ptr[N] = E;
    }
}

__global__ __launch_bounds__(256) void scanC_kernel(const int* __restrict__ in_cnt,
                                                    const int* __restrict__ bsum,
                                                    int* cursorN, int* row_ptr, int N) {
    __shared__ int part[256];
    const int t = threadIdx.x;
    const int base = blockIdx.x * SCAN_CHUNK + t * 4;
    int v[4] = {0, 0, 0, 0};
    #pragma unroll
    for (int i = 0; i < 4; ++i) if (base + i < N) v[i] = in_cnt[base + i];
    const int s = v[0] + v[1] + v[2] + v[3];
    part[t] = s;
    __syncthreads();
    for (int off = 1; off < 256; off <<= 1) {
        int add = (t >= off) ? part[t - off] : 0;
        __syncthreads();
        part[t] += add;
        __syncthreads();
    }
    int a = bsum[blockIdx.x] + part[t] - s;
    #pragma unroll
    for (int i = 0; i < 4; ++i) {
        if (base + i < N) { cursorN[base + i] = a; row_ptr[base + i] = a; }
        a += v[i];
    }
}

// fused scatter: blocks [0, nbN) node-bucket scatter; [nbN, nbN+nbE) edge scatter.
__global__ __launch_bounds__(256) void scatter_kernel(
    const int* __restrict__ ei, const float* __restrict__ ea, const int* __restrict__ deg,
    int* nb_cursor, int* node_list,
    int* cursorN, int* eb_cursor, int* src_csr, int* csr2bkt, float* ea_bkt,
    int N, int E, int nbN)
{
    __shared__ int h[MAXD];
    __shared__ int base[MAXD];
    const int t = threadIdx.x;
    if (t < MAXD) h[t] = 0;
    __syncthreads();

    if (blockIdx.x < nbN) {
        const int n = blockIdx.x * 256 + t;
        int b = 0, loc = 0;
        const bool valid = n < N;
        if (valid) {
            int dg = deg[n];
            b = (dg < MAXD - 1) ? dg : (MAXD - 1);
            loc = atomicAdd(&h[b], 1);
        }
        __syncthreads();
        if (t < MAXD) base[t] = (h[t] > 0) ? atomicAdd(&nb_cursor[t], h[t]) : 0;
        __syncthreads();
        if (valid) node_list[base[b] + loc] = n;
    } else {
        const int e = (blockIdx.x - nbN) * 256 + t;
        const bool valid = e < E;
        int s = 0, d = 0, b = 0, loc = 0;
        if (valid) {
            s = ei[e]; d = ei[E + e];
            int dg = deg[s];
            b = (dg < MAXD - 1) ? dg : (MAXD - 1);
            loc = atomicAdd(&h[b], 1);
        }
        __syncthreads();
        if (t < MAXD) base[t] = (h[t] > 0) ? atomicAdd(&eb_cursor[t], h[t]) : 0;
        __syncthreads();
        if (valid) {
            const int posz = base[b] + loc;
            const int pos = atomicAdd(&cursorN[d], 1);
            src_csr[pos] = s;
            csr2bkt[pos] = posz;
            const float4* p = (const float4*)(ea + (size_t)e * ECH);
            float4* o = (float4*)(ea_bkt + (size_t)posz * ECH);
            o[0] = p[0]; o[1] = p[1]; o[2] = p[2]; o[3] = p[3];
        }
    }
}

// ---------------- fused: z-GEMM (all ts) + y transform (t=0) ----------------
// zgemm blocks first [0, ZB); y(t=0) blocks after [ZB, ZB+nblkY).
// Independent work shares one dispatch so y0 fills zgemm's idle wave slots.

struct ZSh {
    float Ez[ECH][TILE_Z + 4];
    int ebase_s[MAXD + 1];
};
struct YSh {
    float Ws[IN][IN];
    float Ms[IN][TILE_N + 4];
    int id_s[TILE_N];
    int bkt_s[TILE_N];
};

__global__ __launch_bounds__(256) void zy_kernel(
    const float* __restrict__ ea_bkt, __half* __restrict__ zs,
    const int* __restrict__ eb_base, const float* __restrict__ Wmsg,
    int E, int ntiles, int ZB,
    const float* __restrict__ xin, float* __restrict__ y,
    const int* __restrict__ node_list, const int* __restrict__ deg, int N)
{
    __shared__ union { ZSh z; YSh y; } sh;
    const int t = threadIdx.x;

    if (blockIdx.x < ZB) {
        // ---- zgemm path (R18 configuration) ----
        const int bid = blockIdx.x;
        const int tt = bid / ntiles;
        const int i0 = (bid % ntiles) * TILE_Z;
        const float* Wt = Wmsg + (size_t)tt * MAXD * KD * IN;
        __half* zt = zs + (size_t)tt * E * IN;
        const int ntile = min(TILE_Z, E - i0);

        if (t <= MAXD) sh.z.ebase_s[t] = eb_base[t];
        {
            const int e = t >> 1;
            const int j0 = (t & 1) * 8;
            const bool valid = e < ntile;
            const float4 z4 = make_float4(0.f, 0.f, 0.f, 0.f);
            const float* ep = ea_bkt + (size_t)(i0 + e) * ECH + j0;
            #pragma unroll
            for (int i = 0; i < 8; i += 4) {
                float4 v = valid ? *(const float4*)(ep + i) : z4;
                sh.z.Ez[j0 + i + 0][e] = v.x; sh.z.Ez[j0 + i + 1][e] = v.y;
                sh.z.Ez[j0 + i + 2][e] = v.z; sh.z.Ez[j0 + i + 3][e] = v.w;
            }
        }
        __syncthreads();

        const int eg8 = (t >> 4) * 8;
        const int cg4 = (t & 15) * 4;

        int b = 0;
        #pragma unroll
        for (int q = 1; q < MAXD; ++q) if (sh.z.ebase_s[q] <= i0) b = q;

        for (; b < MAXD; ++b) {
            const int slo = max(sh.z.ebase_s[b] - i0, 0);
            const int shi = min(sh.z.ebase_s[b + 1] - i0, ntile);
            if (shi > slo) {
                const float* wp = Wt + ((size_t)b * KD + IN) * IN + cg4;

                float acc[8][4];
                #pragma unroll
                for (int e2 = 0; e2 < 8; ++e2)
                    #pragma unroll
                    for (int c = 0; c < 4; ++c) acc[e2][c] = 0.f;

                #pragma unroll
                for (int half = 0; half < 2; ++half) {
                    float4 w[8];
                    #pragma unroll
                    for (int k = 0; k < 8; ++k)
                        w[k] = *(const float4*)(wp + (size_t)(half * 8 + k) * IN);
                    #pragma unroll
                    for (int k = 0; k < 8; ++k) {
                        const int kk = half * 8 + k;
                        const float4 m0 = *(const float4*)&sh.z.Ez[kk][eg8];
                        const float4 m1 = *(const float4*)&sh.z.Ez[kk][eg8 + 4];
                        const float me[8] = {m0.x, m0.y, m0.z, m0.w,
                                             m1.x, m1.y, m1.z, m1.w};
                        #pragma unroll
                        for (int e2 = 0; e2 < 8; ++e2) {
                            acc[e2][0] += me[e2] * w[k].x;
                            acc[e2][1] += me[e2] * w[k].y;
                            acc[e2][2] += me[e2] * w[k].z;
                            acc[e2][3] += me[e2] * w[k].w;
                        }
                    }
                }

                #pragma unroll
                for (int e2 = 0; e2 < 8; ++e2) {
                    const int el = eg8 + e2;
                    if (el >= slo && el < shi) {
                        union { __half2 h[2]; unsigned long long u; } pk;
                        pk.h[0] = __floats2half2_rn(acc[e2][0], acc[e2][1]);
                        pk.h[1] = __floats2half2_rn(acc[e2][2], acc[e2][3]);
                        __builtin_nontemporal_store(pk.u,
                            (unsigned long long*)(zt + (size_t)(i0 + el) * IN + cg4));
                    }
                }
            }
            if (sh.z.ebase_s[b + 1] >= i0 + ntile) break;
        }
    } else {
        // ---- y(t=0) path ----
        const int i0 = (blockIdx.x - ZB) * TILE_N;
        const int ntile = min(TILE_N, N - i0);
        const float* Wt = Wmsg;   // tt = 0

        {
            const int e = t >> 2;
            const bool valid = e < ntile;
            const int c0 = (t & 3) * 16;
            const float4 z4 = make_float4(0.f, 0.f, 0.f, 0.f);
            int node = valid ? node_list[i0 + e] : 0;
            const float* xp = xin + (size_t)node * IN + c0;
            #pragma unroll
            for (int i = 0; i < 16; i += 4) {
                float4 v = valid ? *(const float4*)(xp + i) : z4;
                sh.y.Ms[c0 + i + 0][e] = v.x; sh.y.Ms[c0 + i + 1][e] = v.y;
                sh.y.Ms[c0 + i + 2][e] = v.z; sh.y.Ms[c0 + i + 3][e] = v.w;
            }
            if (t < TILE_N) {
                if (t < ntile) {
                    int id = node_list[i0 + t];
                    sh.y.id_s[t] = id;
                    int dg = deg[id];
                    sh.y.bkt_s[t] = (dg < MAXD - 1) ? dg : (MAXD - 1);
                } else { sh.y.id_s[t] = 0; sh.y.bkt_s[t] = -1; }
            }
        }
        __syncthreads();

        const int b_first = sh.y.bkt_s[0];
        const int b_last = sh.y.bkt_s[ntile - 1];
        const int eg4 = (t >> 4) * 4;
        const int cg4 = (t & 15) * 4;

        for (int b = b_first; b <= b_last; ++b) {
            if (b != b_first) __syncthreads();
            {
                const float4* Wb = (const float4*)(Wt + (size_t)b * KD * IN);
                float4* Wsp = (float4*)sh.y.Ws;
                #pragma unroll
                for (int q = 0; q < 4; ++q) Wsp[t + q * 256] = Wb[t + q * 256];
            }
            __syncthreads();

            float acc[4][4];
            #pragma unroll
            for (int e2 = 0; e2 < 4; ++e2)
                #pragma unroll
                for (int c = 0; c < 4; ++c) acc[e2][c] = 0.f;

            #pragma unroll 8
            for (int k = 0; k < IN; ++k) {
                const float4 w = *(const float4*)&sh.y.Ws[k][cg4];
                const float4 m = *(const float4*)&sh.y.Ms[k][eg4];
                const float me[4] = {m.x, m.y, m.z, m.w};
                #pragma unroll
                for (int e2 = 0; e2 < 4; ++e2) {
                    acc[e2][0] += me[e2] * w.x;
                    acc[e2][1] += me[e2] * w.y;
                    acc[e2][2] += me[e2] * w.z;
                    acc[e2][3] += me[e2] * w.w;
                }
            }

            #pragma unroll
            for (int e2 = 0; e2 < 4; ++e2) {
                const int el = eg4 + e2;
                if (el < ntile && sh.y.bkt_s[el] == b) {
                    const size_t o = (size_t)sh.y.id_s[el] * IN + cg4;
                    *(float4*)(y + o) = make_float4(acc[e2][0], acc[e2][1],
                                                    acc[e2][2], acc[e2][3]);
                }
            }
        }
    }
}

// ---------------- per-timestep: node transform y = Wx[b]^T x (tt >= 1) ----------------

__global__ __launch_bounds__(256) void y_kernel(
    const float* __restrict__ xin, float* __restrict__ y,
    const int* __restrict__ node_list, const int* __restrict__ deg,
    const float* __restrict__ Wt, int N)
{
    __shared__ float Ws[IN][IN];           // 16 KB
    __shared__ float Ms[IN][TILE_N + 4];   // 17.4 KB
    __shared__ int id_s[TILE_N];
    __shared__ int bkt_s[TILE_N];

    const int t = threadIdx.x;
    const int i0 = blockIdx.x * TILE_N;
    const int ntile = min(TILE_N, N - i0);

    {
        const int e = t >> 2;
        const bool valid = e < ntile;
        const int c0 = (t & 3) * 16;
        const float4 z4 = make_float4(0.f, 0.f, 0.f, 0.f);
        int node = valid ? node_list[i0 + e] : 0;
        const float* xp = xin + (size_t)node * IN + c0;
        #pragma unroll
        for (int i = 0; i < 16; i += 4) {
            float4 v = valid ? *(const float4*)(xp + i) : z4;
            Ms[c0 + i + 0][e] = v.x; Ms[c0 + i + 1][e] = v.y;
            Ms[c0 + i + 2][e] = v.z; Ms[c0 + i + 3][e] = v.w;
        }
        if (t < TILE_N) {
            if (t < ntile) {
                int id = node_list[i0 + t];
                id_s[t] = id;
                int dg = deg[id];
                bkt_s[t] = (dg < MAXD - 1) ? dg : (MAXD - 1);
            } else { id_s[t] = 0; bkt_s[t] = -1; }
        }
    }
    __syncthreads();

    const int b_first = bkt_s[0];
    const int b_last = bkt_s[ntile - 1];
    const int eg4 = (t >> 4) * 4;
    const int cg4 = (t & 15) * 4;

    for (int b = b_first; b <= b_last; ++b) {
        if (b != b_first) __syncthreads();
        {
            const float4* Wb = (const float4*)(Wt + (size_t)b * KD * IN);
            float4* Wsp = (float4*)Ws;
            #pragma unroll
            for (int q = 0; q < 4; ++q) Wsp[t + q * 256] = Wb[t + q * 256];
        }
        __syncthreads();

        float acc[4][4];
        #pragma unroll
        for (int e2 = 0; e2 < 4; ++e2)
            #pragma unroll
            for (int c = 0; c < 4; ++c) acc[e2][c] = 0.f;

        #pragma unroll 8
        for (int k = 0; k < IN; ++k) {
            const float4 w = *(const float4*)&Ws[k][cg4];
            const float4 m = *(const float4*)&Ms[k][eg4];
            const float me[4] = {m.x, m.y, m.z, m.w};
            #pragma unroll
            for (int e2 = 0; e2 < 4; ++e2) {
                acc[e2][0] += me[e2] * w.x;
                acc[e2][1] += me[e2] * w.y;
                acc[e2][2] += me[e2] * w.z;
                acc[e2][3] += me[e2] * w.w;
            }
        }

        #pragma unroll
        for (int e2 = 0; e2 < 4; ++e2) {
            const int el = eg4 + e2;
            if (el < ntile && bkt_s[el] == b) {
                const size_t o = (size_t)id_s[el] * IN + cg4;
                *(float4*)(y + o) = make_float4(acc[e2][0], acc[e2][1],
                                                acc[e2][2], acc[e2][3]);
            }
        }
    }
}

// ---------------- per-timestep: lean aggregation (no W, no LDS) ----------------

__global__ __launch_bounds__(AGG_BLOCK) void aggS_kernel(
    const float* __restrict__ y, float* __restrict__ out,
    const int* __restrict__ row_ptr, const int* __restrict__ src_csr,
    const int* __restrict__ csr2bkt, const __half* __restrict__ zt, int N)
{
    const int t = threadIdx.x;
    const int lane = t & 63;
    const int grp = lane >> 4;
    const int gl = lane & 15;
    const int c0 = gl * 4;
    const int d = blockIdx.x * AGG_DPB + (t >> 6) * 4 + grp;
    if (d >= N) return;
    const int lane0 = grp * 16;

    const int p0 = row_ptr[d];
    const int p1 = row_ptr[d + 1];

    float4 acc = make_float4(0.f, 0.f, 0.f, 0.f);

    for (int p = p0; p < p1; p += 8) {
        const int cnt = min(8, p1 - p);
        const int mi = p + (gl & 7);
        int s_r = 0, z_r = 0;
        if (mi < p1) { s_r = src_csr[mi]; z_r = csr2bkt[mi]; }

        float4 yv[8];
        uint2 zu[8];
        #pragma unroll
        for (int i = 0; i < 8; ++i) {
            int si = __shfl(s_r, lane0 + i);
            int zi = __shfl(z_r, lane0 + i);
            if (i < cnt) {
                yv[i] = *(const float4*)(y + (size_t)si * IN + c0);
                zu[i] = *(const uint2*)(zt + (size_t)zi * IN + c0);
            }
        }
        #pragma unroll
        for (int i = 0; i < 8; ++i) {
            if (i < cnt) {
                const __half2* zh = (const __half2*)&zu[i];
                float2 z01 = __half22float2(zh[0]);
                float2 z23 = __half22float2(zh[1]);
                acc.x += sigmoidf(yv[i].x + z01.x);
                acc.y += sigmoidf(yv[i].y + z01.y);
                acc.z += sigmoidf(yv[i].z + z23.x);
                acc.w += sigmoidf(yv[i].w + z23.y);
            }
        }
    }

    const float4 yd = *(const float4*)(y + (size_t)d * IN + c0);
    float4 r = make_float4(sigmoidf(yd.x) + acc.x, sigmoidf(yd.y) + acc.y,
                           sigmoidf(yd.z) + acc.z, sigmoidf(yd.w) + acc.w);
    *(float4*)(out + (size_t)d * IN + c0) = r;
}

// ---------------- readout + pooling ----------------

__global__ __launch_bounds__(256) void readout_kernel(
    const float* __restrict__ x, const float* __restrict__ Wr,
    const int* __restrict__ batch, float* __restrict__ pooled, int N)
{
    __shared__ float Wr_s[TSTEPS][10][IN];
    __shared__ float pool_s[64 * 10];
    const int t = threadIdx.x;
    for (int idx = t; idx < TSTEPS * IN * 10; idx += 256) {
        int tt = idx / (IN * 10);
        int r = idx % (IN * 10);
        int k = r / 10;
        int j = r % 10;
        Wr_s[tt][j][k] = Wr[idx];
    }
    for (int idx = t; idx < 64 * 10; idx += 256) pool_s[idx] = 0.f;
    __syncthreads();

    const int n = blockIdx.x * 256 + t;
    if (n < N) {
        float xr[IN];
        const float4* xp = (const float4*)(x + (size_t)n * IN);
        #pragma unroll
        for (int i = 0; i < IN / 4; ++i) ((float4*)xr)[i] = xp[i];
        float out10[10];
        #pragma unroll
        for (int j = 0; j < 10; ++j) out10[j] = 0.f;
        for (int tt = 0; tt < TSTEPS; ++tt) {
            float lg[10];
            #pragma unroll
            for (int j = 0; j < 10; ++j) {
                const float4* wp = (const float4*)Wr_s[tt][j];
                float s = 0.f;
                #pragma unroll
                for (int i = 0; i < IN / 4; ++i) {
                    float4 w = wp[i];
                    float4 xv = ((const float4*)xr)[i];
                    s += w.x * xv.x + w.y * xv.y + w.z * xv.z + w.w * xv.w;
                }
                lg[j] = s;
            }
            float mx = lg[0];
            #pragma unroll
            for (int j = 1; j < 10; ++j) mx = fmaxf(mx, lg[j]);
            float sum = 0.f;
            #pragma unroll
            for (int j = 0; j < 10; ++j) { lg[j] = __expf(lg[j] - mx); sum += lg[j]; }
            float inv = 1.f / sum;
            #pragma unroll
            for (int j = 0; j < 10; ++j) out10[j] += lg[j] * inv;
        }
        const int g = batch[n];
        #pragma unroll
        for (int j = 0; j < 10; ++j) atomicAdd(&pool_s[g * 10 + j], out10[j]);
    }
    __syncthreads();
    for (int idx = t; idx < 64 * 10; idx += 256) {
        float v = pool_s[idx];
        if (v != 0.f) atomicAdd(&pooled[idx], v);
    }
}

// ---------------- final MLP ----------------

__global__ __launch_bounds__(256) void mlp_kernel(
    const float* __restrict__ pooled,
    const float* __restrict__ fc1w, const float* __restrict__ fc1b,
    const float* __restrict__ fc2w, const float* __restrict__ fc2b,
    const float* __restrict__ fc3w, const float* __restrict__ fc3b,
    float* __restrict__ out, int G)
{
    __shared__ float p_s[64 * 10];
    __shared__ float h1[64 * 128];
    __shared__ float h2[64 * 64];
    const int t = threadIdx.x;
    for (int idx = t; idx < G * 10; idx += 256) p_s[idx] = pooled[idx];
    __syncthreads();
    for (int idx = t; idx < G * 128; idx += 256) {
        int g = idx >> 7, j = idx & 127;
        float s = fc1b[j];
        #pragma unroll
        for (int k = 0; k < 10; ++k) s += p_s[g * 10 + k] * fc1w[k * 128 + j];
        h1[idx] = (s > 0.f) ? s : 0.01f * s;
    }
    __syncthreads();
    for (int idx = t; idx < G * 64; idx += 256) {
        int g = idx >> 6, j = idx & 63;
        float s = fc2b[j];
        for (int k = 0; k < 128; ++k) s += h1[(g << 7) + k] * fc2w[(k << 6) + j];
        h2[idx] = (s > 0.f) ? s : 0.01f * s;
    }
    __syncthreads();
    if (t < G) {
        float s = fc3b[0];
        for (int k = 0; k < 64; ++k) s += h2[(t << 6) + k] * fc3w[k];
        out[t] = (s > 0.f) ? s : 0.01f * s;
    }
}

// ---------------- launch ----------------

extern "C" void kernel_launch(void* const* d_in, const int* in_sizes, int n_in,
                              void* d_out, int out_size, void* d_ws, size_t ws_size,
                              hipStream_t stream)
{
    const float* x     = (const float*)d_in[0];
    const float* ea    = (const float*)d_in[1];
    const float* Wmsg  = (const float*)d_in[2];
    const float* Wread = (const float*)d_in[3];
    const float* fc1w  = (const float*)d_in[4];
    const float* fc1b  = (const float*)d_in[5];
    const float* fc2w  = (const float*)d_in[6];
    const float* fc2b  = (const float*)d_in[7];
    const float* fc3w  = (const float*)d_in[8];
    const float* fc3b  = (const float*)d_in[9];
    const int* ei      = (const int*)d_in[10];
    const int* batch   = (const int*)d_in[11];

    const int N = in_sizes[0] / IN;
    const int E = in_sizes[10] / 2;
    const int nscan = (N + SCAN_CHUNK - 1) / SCAN_CHUNK;
    const int ntilesZ = (E + TILE_Z - 1) / TILE_Z;
    const int ZB = TSTEPS * ntilesZ;

    char* ws = (char*)d_ws;
    size_t off = 0;
    auto take = [&](size_t bytes) {
        char* p = ws + off;
        off = (off + bytes + 255) & ~(size_t)255;
        return p;
    };
    // zero-region: [meta | pooled | deg | in_cnt] — single memset per launch
    int* meta      = (int*)take(512);
    float* pooled  = (float*)take(64 * 10 * 4);
    int* deg       = (int*)take((size_t)N * 4);
    int* in_cnt    = (int*)take((size_t)N * 4);
    const size_t zero_bytes = (size_t)((char*)in_cnt - (char*)meta) + (size_t)N * 4;
    int* bsum      = (int*)take((size_t)nscan * 4);
    int* node_list = (int*)take((size_t)N * 4);
    int* cursorN   = (int*)take((size_t)N * 4);
    int* row_ptr   = (int*)take((size_t)(N + 1) * 4);
    int* src_csr   = (int*)take((size_t)E * 4);
    int* csr2bkt   = (int*)take((size_t)E * 4);
    float* ea_bkt  = (float*)take((size_t)E * ECH * 4);
    __half* zs     = (__half*)take((size_t)TSTEPS * E * IN * 2);  // 82 MB fp16
    float* ybuf    = (float*)take((size_t)N * IN * 4);
    float* xbA     = (float*)take((size_t)N * IN * 4);
    float* xbB     = (float*)take((size_t)N * IN * 4);

    int* nb_cnt    = meta;        // [0..9]
    int* nb_cursor = meta + 16;   // [16..25]
    int* eb_cnt    = meta + 32;   // [32..41]
    int* eb_cursor = meta + 48;   // [48..57]
    int* eb_base   = meta + 64;   // [64..74]

    const int nbN = (N + 255) / 256;
    const int nbE = (E + 255) / 256;
    const int nblkY = (N + TILE_N - 1) / TILE_N;
    const int nblkA = (N + AGG_DPB - 1) / AGG_DPB;

    hipMemsetAsync(meta, 0, zero_bytes, stream);
    hist_kernel<<<nbE, 256, 0, stream>>>(ei, deg, in_cnt, E);
    scanA_kernel<<<nscan, 256, 0, stream>>>(in_cnt, deg, bsum, nb_cnt, eb_cnt, N);
    scanB_kernel<<<1, 256, 0, stream>>>(bsum, nscan, nb_cnt, nb_cursor,
                                        eb_cnt, eb_cursor, eb_base, row_ptr, N, E);
    scanC_kernel<<<nscan, 256, 0, stream>>>(in_cnt, bsum, cursorN, row_ptr, N);
    scatter_kernel<<<nbN + nbE, 256, 0, stream>>>(ei, ea, deg, nb_cursor, node_list,
                                                  cursorN, eb_cursor, src_csr, csr2bkt,
                                                  ea_bkt, N, E, nbN);
    // fused: zgemm (all timesteps) + y(t=0)
    zy_kernel<<<ZB + nblkY, 256, 0, stream>>>(ea_bkt, zs, eb_base, Wmsg,
                                              E, ntilesZ, ZB,
                                              x, ybuf, node_list, deg, N);

    const float* xi = x;
    float* bufs[2] = {xbA, xbB};
    for (int tt = 0; tt < TSTEPS; ++tt) {
        if (tt > 0) {
            const float* Wt = Wmsg + (size_t)tt * MAXD * KD * IN;
            y_kernel<<<nblkY, 256, 0, stream>>>(xi, ybuf, node_list, deg, Wt, N);
        }
        float* xo = bufs[tt & 1];
        aggS_kernel<<<nblkA, AGG_BLOCK, 0, stream>>>(ybuf, xo, row_ptr, src_csr,
                                                     csr2bkt,
                                                     zs + (size_t)tt * E * IN, N);
        xi = xo;
    }

    readout_kernel<<<nbN, 256, 0, stream>>>(xi, Wread, batch, pooled, N);
    mlp_kernel<<<1, 256, 0, stream>>>(pooled, fc1w, fc1b, fc2w, fc2b, fc3w, fc3b,
                                      (float*)d_out, out_size);
}